// Round 3
// baseline (57276.740 us; speedup 1.0000x reference)
//
#include <hip/hip_runtime.h>

// ---------------------------------------------------------------------------
// Seq2seq GRU enc (500) -> local attn -> GRU dec (64). Inputs/outputs fp32.
// Precision: bf16x3 operand splits (6 MFMA chains) => fp32-true matmuls;
// sig->pt path fp64 (pt floor needs sig err < ~2e-7).
//
// R3 (R2 ideas at R1's 225MB footprint):
//  - Producers: plain stores; barrier RELEASE flag store (wbl2) pushes dirty
//    lines to LLC (R1-validated). Consumers: relaxed agent (sc1) atomic
//    loads for cross-WG state (h/c planes, hf, sig_part) -> read from LLC,
//    NO buffer_inv anywhere -> weights stay L2-resident across steps.
//  - 768 thr/WG (12 waves), GRU K-split 4-way per gate, LDS tree-reduce.
//  - encw fused in encoder, wid<3, kc mod 3: bit-identical to R1. P2/P3 of
//    decoder bit-identical to R1. Only GRU sum grouping differs (~1e-7).
//  - h double-buffered (2 slots), c/hf single buffer. ws ~= 224.8 MB.
// ---------------------------------------------------------------------------

#define B_    64
#define SRCL  500
#define TRGL  64
#define DIM   512
#define H_    1024
#define WIN   13
#define DW    6

// plane strides (elements) of the bf16x3 weight splits
#define EWIHN 1572864   // 3H*DIM
#define EWHHN 3145728   // 3H*H
#define DWIHN 4718592   // 3H*(DIM+H)
#define DWHHN 3145728
#define OUTWN 524288    // DIM*H
#define OWWN  1048576   // H*H
#define ATWN  1048576
#define BH    (B_ * H_)
#define HN    (2 * BH)  // h plane stride (2 slots)
#define CN    BH        // c plane stride

typedef __attribute__((ext_vector_type(8)))  short short8;
typedef __attribute__((ext_vector_type(16))) float floatx16;

#define MFMA(a, b, c) __builtin_amdgcn_mfma_f32_32x32x16_bf16((a), (b), (c), 0, 0, 0)

__device__ __forceinline__ float bf2f(short s) {
  union { unsigned int u; float f; } v;
  v.u = ((unsigned int)(unsigned short)s) << 16;
  return v.f;
}
__device__ __forceinline__ short f2bf(float f) {
  union { float f; unsigned int u; } v;
  v.f = f;
  unsigned int u = v.u;
  u = (u + 0x7fffu + ((u >> 16) & 1u)) >> 16;  // RNE
  return (short)u;
}
__device__ __forceinline__ floatx16 zero16() {
  floatx16 z;
#pragma unroll
  for (int i = 0; i < 16; ++i) z[i] = 0.f;
  return z;
}
__device__ __forceinline__ float sigm(float x) { return 1.f / (1.f + expf(-x)); }

// ---- coherent (agent-scope sc1, relaxed) loads: read from LLC, no inv ----
__device__ __forceinline__ short8 load_c16(const short* p) {
  unsigned long long lo = __hip_atomic_load(
      (const unsigned long long*)p, __ATOMIC_RELAXED, __HIP_MEMORY_SCOPE_AGENT);
  unsigned long long hi = __hip_atomic_load(
      (const unsigned long long*)(p + 4), __ATOMIC_RELAXED,
      __HIP_MEMORY_SCOPE_AGENT);
  union { unsigned long long u[2]; short8 s; } x;
  x.u[0] = lo; x.u[1] = hi;
  return x.s;
}
__device__ __forceinline__ float load_c4f(const float* p) {
  unsigned int u = __hip_atomic_load((const unsigned int*)p, __ATOMIC_RELAXED,
                                     __HIP_MEMORY_SCOPE_AGENT);
  union { unsigned int u; float f; } x;
  x.u = u;
  return x.f;
}
__device__ __forceinline__ double load_c8d(const double* p) {
  unsigned long long u = __hip_atomic_load(
      (const unsigned long long*)p, __ATOMIC_RELAXED, __HIP_MEMORY_SCOPE_AGENT);
  union { unsigned long long u; double d; } x;
  x.u = u;
  return x.d;
}

// 8 fp32 -> 3 bf16 planes (register split; v-s0 exact in fp32)
__device__ __forceinline__ void split8(const float* p, short8& a0, short8& a1,
                                       short8& a2) {
#pragma unroll
  for (int j = 0; j < 8; ++j) {
    float v = p[j];
    short s0 = f2bf(v);
    float r = v - bf2f(s0);
    short s1 = f2bf(r);
    r -= bf2f(s1);
    a0[j] = s0; a1[j] = s1; a2[j] = f2bf(r);
  }
}

__device__ __forceinline__ void publish_h(short* hw, int base, float hn) {
  short s0 = f2bf(hn);
  float rr = hn - bf2f(s0);
  short s1 = f2bf(rr);
  hw[base] = s0;
  hw[HN + base] = s1;
  hw[2 * HN + base] = f2bf(rr - bf2f(s1));
}

#define DECL6(P) floatx16 P##00 = zero16(), P##01 = zero16(), \
                          P##10 = zero16(), P##2 = zero16();
#define SUM6(P, r) (P##00[r] + P##01[r] + P##10[r] + P##2[r])

// plain-load A (weights are plain everywhere; also used for read-only inputs)
#define LOADA(a0v, a1v, a2v, ap, AN, kc)                                    \
  const short8 a0v = *(const short8*)((ap) + (size_t)(kc)*16);              \
  const short8 a1v = *(const short8*)((ap) + (size_t)(AN) + (size_t)(kc)*16); \
  const short8 a2v = *(const short8*)((ap) + 2*(size_t)(AN) + (size_t)(kc)*16);

// coherent-load A (cross-WG mutable state: h planes, c planes)
#define LOADA_C(a0v, a1v, a2v, ap, AN, kc)                                  \
  const short8 a0v = load_c16((ap) + (size_t)(kc)*16);                      \
  const short8 a1v = load_c16((ap) + (size_t)(AN) + (size_t)(kc)*16);       \
  const short8 a2v = load_c16((ap) + 2*(size_t)(AN) + (size_t)(kc)*16);

#define CHUNK6(P, a0v, a1v, a2v, bp, BN, kc)                                 \
  {                                                                          \
    const short8 b0v = *(const short8*)((bp) + (size_t)(kc)*16);             \
    const short8 b1v = *(const short8*)((bp) + (size_t)(BN) + (size_t)(kc)*16); \
    const short8 b2v = *(const short8*)((bp) + 2*(size_t)(BN) + (size_t)(kc)*16); \
    P##00 = MFMA(a0v, b0v, P##00);                                           \
    P##01 = MFMA(a0v, b1v, P##01);                                           \
    P##10 = MFMA(a1v, b0v, P##10);                                           \
    P##2  = MFMA(a0v, b2v, P##2);                                            \
    P##2  = MFMA(a1v, b1v, P##2);                                            \
    P##2  = MFMA(a2v, b0v, P##2);                                            \
  }

// C-fragment scatter
#define WRITE_TILE(dst, EXPR)                                        \
  do {                                                               \
    _Pragma("unroll") for (int r = 0; r < 16; ++r) {                 \
      int row_ = (r & 3) + 8 * (r >> 2) + 4 * (lane >> 5);           \
      (dst)[row_ * 32 + ra] = (EXPR);                                \
    }                                                                \
  } while (0)

// Barrier: syncthreads (compiler drains vmcnt before s_barrier), RELEASE
// agent flag store (emits wbl2 -> dirty lines to LLC; clean weight lines in
// every L2 stay VALID), relaxed poll (sc1 loads see LLC), workgroup-scope
// acquire fence (ordering only, no cache op), syncthreads.
__device__ __forceinline__ void group_barrier(int* flags, int group_base,
                                              int my_wg, int epoch, int tid) {
  __syncthreads();
  if (tid == 0)
    __hip_atomic_store(&flags[my_wg], epoch, __ATOMIC_RELEASE,
                       __HIP_MEMORY_SCOPE_AGENT);
  const int idx = group_base + (tid & 31);
  while (__hip_atomic_load(&flags[idx], __ATOMIC_RELAXED,
                           __HIP_MEMORY_SCOPE_AGENT) < epoch)
    __builtin_amdgcn_s_sleep(1);
  __builtin_amdgcn_fence(__ATOMIC_ACQUIRE, "workgroup");
  __syncthreads();
}

// fp32 -> 3 bf16 planes (weights, done once)
__global__ void split3_kernel(const float* __restrict__ in,
                              short* __restrict__ out, int n) {
  const int i = blockIdx.x * 256 + threadIdx.x;
  if (i >= n) return;
  float v = in[i];
  short s0 = f2bf(v);
  float r = v - bf2f(s0);
  short s1 = f2bf(r);
  r -= bf2f(s1);
  out[i] = s0;
  out[n + i] = s1;
  out[2 * n + i] = f2bf(r);
}

// ---------------------------------------------------------------------------
// Encoder + fused attn transform (enc_w row t-1 each iter, wid<3, kc mod 3 —
// bit-identical to R1). GRU: 12 waves, wave=(gate g, K-quarter q).
// ---------------------------------------------------------------------------
__global__ __launch_bounds__(768) void enc_kernel(
    const float* __restrict__ src, const short* __restrict__ Wih,
    const short* __restrict__ Whh, const float* __restrict__ bih,
    const float* __restrict__ bhh, const short* __restrict__ attnW,
    const float* __restrict__ attn_b, float* __restrict__ h_f32,
    short* __restrict__ h_pl, float* __restrict__ enc_w,
    int* __restrict__ flags) {
  const int tid  = threadIdx.x;
  const int lane = tid & 63;
  const int wid  = tid >> 6;   // 0..11
  const int g    = wid >> 2;   // gate 0..2
  const int q    = wid & 3;    // K-quarter
  const int m    = blockIdx.x >> 5;
  const int js   = blockIdx.x & 31;
  const int ra   = lane & 31;
  const int koff = (lane >> 5) * 8;

  __shared__ float lds[16][1024];

  const int nrow = g * H_ + js * 32 + ra;
  const short* wih_p = Wih + (size_t)nrow * DIM + koff;
  const short* whh_p = Whh + (size_t)nrow * H_ + koff;
  const short* atw_p = attnW + (size_t)(js * 32 + ra) * H_ + koff;
  const float* src_p = src + (size_t)(m * 32 + ra) * (SRCL * DIM) + koff;
  const int hrow = (m * 32 + ra) * H_ + koff;

  const int group_base = m * 32;
  const int my_wg = blockIdx.x;

  for (int t = 0; t < SRCL; ++t) {
    const short* hp = h_pl + (t & 1) * BH + hrow;

    // ---- fused attn: enc_w row t-1 from h slot (t&1); wid<3, kc mod 3 ----
    if (t > 0) {
      if (wid < 3) {
        DECL6(qa);
        for (int kc = wid; kc < H_ / 16; kc += 3) {
          LOADA_C(a0v, a1v, a2v, hp, HN, kc);
          CHUNK6(qa, a0v, a1v, a2v, atw_p, ATWN, kc);
        }
        WRITE_TILE(lds[wid], SUM6(qa, r));
      }
      __syncthreads();
      for (int idx = tid; idx < 1024; idx += 768) {
        const int bl = idx >> 5, j = idx & 31;
        float v = lds[0][idx] + lds[1][idx] + lds[2][idx] + attn_b[js * 32 + j];
        enc_w[((size_t)(m * 32 + bl) * SRCL + (t - 1)) * H_ + js * 32 + j] = v;
      }
      __syncthreads();
    }

    // ---- GRU matmuls, 4-way K-split per gate ----
    const float* xp = src_p + (size_t)t * DIM;
    if (g < 2) {
      DECL6(qa);
#pragma unroll 4
      for (int kc = q * 8; kc < q * 8 + 8; ++kc) {
        short8 a0v, a1v, a2v;
        split8(xp + kc * 16, a0v, a1v, a2v);
        CHUNK6(qa, a0v, a1v, a2v, wih_p, EWIHN, kc);
      }
#pragma unroll 4
      for (int kc = q * 16; kc < q * 16 + 16; ++kc) {
        LOADA_C(a0v, a1v, a2v, hp, HN, kc);
        CHUNK6(qa, a0v, a1v, a2v, whh_p, EWHHN, kc);
      }
      WRITE_TILE(lds[wid], SUM6(qa, r));
    } else {
      {
        DECL6(qa);
#pragma unroll 4
        for (int kc = q * 8; kc < q * 8 + 8; ++kc) {
          short8 a0v, a1v, a2v;
          split8(xp + kc * 16, a0v, a1v, a2v);
          CHUNK6(qa, a0v, a1v, a2v, wih_p, EWIHN, kc);
        }
        WRITE_TILE(lds[8 + q], SUM6(qa, r));
      }
      {
        DECL6(qb);
#pragma unroll 4
        for (int kc = q * 16; kc < q * 16 + 16; ++kc) {
          LOADA_C(a0v, a1v, a2v, hp, HN, kc);
          CHUNK6(qb, a0v, a1v, a2v, whh_p, EWHHN, kc);
        }
        WRITE_TILE(lds[12 + q], SUM6(qb, r));
      }
    }
    __syncthreads();

    // ---- elementwise + publish h (plain stores; barrier wbl2 flushes) ----
    short* h0w = h_pl + ((t + 1) & 1) * BH;
    for (int idx = tid; idx < 1024; idx += 768) {
      const int bl = idx >> 5, j = idx & 31;
      const int jg = js * 32 + j;
      const int bg = m * 32 + bl;
      float pr = ((lds[0][idx] + lds[1][idx]) + (lds[2][idx] + lds[3][idx])) +
                 bih[jg] + bhh[jg];
      float pz = ((lds[4][idx] + lds[5][idx]) + (lds[6][idx] + lds[7][idx])) +
                 bih[H_ + jg] + bhh[H_ + jg];
      float gi_n = ((lds[8][idx] + lds[9][idx]) +
                    (lds[10][idx] + lds[11][idx])) + bih[2 * H_ + jg];
      float gh_n = ((lds[12][idx] + lds[13][idx]) +
                    (lds[14][idx] + lds[15][idx])) + bhh[2 * H_ + jg];
      float r_ = sigm(pr), z_ = sigm(pz);
      float n_ = tanhf(gi_n + r_ * gh_n);
      float ho = h_f32[bg * H_ + jg];
      float hn = (1.f - z_) * n_ + z_ * ho;
      h_f32[bg * H_ + jg] = hn;            // enc-private
      publish_h(h0w, bg * H_ + jg, hn);
    }
    group_barrier(flags, group_base, my_wg, t + 1, tid);
  }

  // ---- final fused attn: enc_w row 499 from h slot 0 ----
  {
    const short* hp = h_pl + 0 * BH + hrow;
    if (wid < 3) {
      DECL6(qa);
      for (int kc = wid; kc < H_ / 16; kc += 3) {
        LOADA_C(a0v, a1v, a2v, hp, HN, kc);
        CHUNK6(qa, a0v, a1v, a2v, atw_p, ATWN, kc);
      }
      WRITE_TILE(lds[wid], SUM6(qa, r));
    }
    __syncthreads();
    for (int idx = tid; idx < 1024; idx += 768) {
      const int bl = idx >> 5, j = idx & 31;
      float v = lds[0][idx] + lds[1][idx] + lds[2][idx] + attn_b[js * 32 + j];
      enc_w[((size_t)(m * 32 + bl) * SRCL + (SRCL - 1)) * H_ + js * 32 + j] = v;
    }
  }
}

// ---------------------------------------------------------------------------
// Decoder: 64 WGs x 768 thr, 3 phases per step. P2/P3 bit-identical to R1.
// ---------------------------------------------------------------------------
__global__ __launch_bounds__(768) void dec_kernel(
    const float* __restrict__ trg, const short* __restrict__ Wih,
    const short* __restrict__ Whh, const float* __restrict__ bih,
    const float* __restrict__ bhh, const short* __restrict__ outW,
    const float* __restrict__ outb, const short* __restrict__ owW,
    const float* __restrict__ owb, const float* __restrict__ ovW,
    const float* __restrict__ ovb, const float* __restrict__ enc_w,
    float* __restrict__ h_f32, short* __restrict__ h_pl,
    short* __restrict__ c_pl, double* __restrict__ sig_part,
    int* __restrict__ flags, float* __restrict__ out) {
  const int tid  = threadIdx.x;
  const int lane = tid & 63;
  const int wid  = tid >> 6;   // 0..11
  const int g    = wid >> 2;
  const int q    = wid & 3;
  const int m    = blockIdx.x >> 5;
  const int js   = blockIdx.x & 31;
  const int ra   = lane & 31;
  const int koff = (lane >> 5) * 8;

  __shared__ float lds[16][1024];
  __shared__ float al13[WIN];
  __shared__ float ah13[WIN];

  const int nrow = g * H_ + js * 32 + ra;
  const short* wx_p = Wih + (size_t)nrow * (DIM + H_) + koff;  // x cols
  const short* wc_p = wx_p + DIM;                              // c cols
  const short* wh_p = Whh + (size_t)nrow * H_ + koff;
  const float* trg_p = trg + (size_t)(m * 32 + ra) * (TRGL * DIM) + koff;
  const int hrow = (m * 32 + ra) * H_ + koff;
  const short* cp = c_pl + hrow;
  const short* ow_p = owW + (size_t)(js * 32 + ra) * H_ + koff;
  const short* outw_p = outW + (size_t)((js & 15) * 32 + ra) * H_ + koff;

  const int group_base = m * 32;
  const int my_wg = blockIdx.x;
  const int b3 = blockIdx.x;  // P3: WG <-> batch

  for (int t = 0; t < TRGL; ++t) {
    const int rd = t & 1, wr = (t + 1) & 1;
    const short* hp = h_pl + rd * BH + hrow;

    // ---- P1: GRU, 4-way K-split. gi over [x_t, c]; gh over h ----
    if (g < 2) {
      DECL6(qa);
      if (t > 0) {
        const float* xp = trg_p + (size_t)(t - 1) * DIM;
#pragma unroll 4
        for (int kc = q * 8; kc < q * 8 + 8; ++kc) {
          short8 a0v, a1v, a2v;
          split8(xp + kc * 16, a0v, a1v, a2v);
          CHUNK6(qa, a0v, a1v, a2v, wx_p, DWIHN, kc);
        }
      }
#pragma unroll 4
      for (int kc = q * 16; kc < q * 16 + 16; ++kc) {
        LOADA_C(a0v, a1v, a2v, cp, CN, kc);
        CHUNK6(qa, a0v, a1v, a2v, wc_p, DWIHN, kc);
      }
#pragma unroll 4
      for (int kc = q * 16; kc < q * 16 + 16; ++kc) {
        LOADA_C(a0v, a1v, a2v, hp, HN, kc);
        CHUNK6(qa, a0v, a1v, a2v, wh_p, DWHHN, kc);
      }
      WRITE_TILE(lds[wid], SUM6(qa, r));
    } else {
      {
        DECL6(qa);
        if (t > 0) {
          const float* xp = trg_p + (size_t)(t - 1) * DIM;
#pragma unroll 4
          for (int kc = q * 8; kc < q * 8 + 8; ++kc) {
            short8 a0v, a1v, a2v;
            split8(xp + kc * 16, a0v, a1v, a2v);
            CHUNK6(qa, a0v, a1v, a2v, wx_p, DWIHN, kc);
          }
        }
#pragma unroll 4
        for (int kc = q * 16; kc < q * 16 + 16; ++kc) {
          LOADA_C(a0v, a1v, a2v, cp, CN, kc);
          CHUNK6(qa, a0v, a1v, a2v, wc_p, DWIHN, kc);
        }
        WRITE_TILE(lds[8 + q], SUM6(qa, r));
      }
      {
        DECL6(qb);
#pragma unroll 4
        for (int kc = q * 16; kc < q * 16 + 16; ++kc) {
          LOADA_C(a0v, a1v, a2v, hp, HN, kc);
          CHUNK6(qb, a0v, a1v, a2v, wh_p, DWHHN, kc);
        }
        WRITE_TILE(lds[12 + q], SUM6(qb, r));
      }
    }
    __syncthreads();
    {
      short* h0w = h_pl + wr * BH;
      for (int idx = tid; idx < 1024; idx += 768) {
        const int bl = idx >> 5, j = idx & 31;
        const int jg = js * 32 + j;
        const int bg = m * 32 + bl;
        float pr = ((lds[0][idx] + lds[1][idx]) + (lds[2][idx] + lds[3][idx])) +
                   bih[jg] + bhh[jg];
        float pz = ((lds[4][idx] + lds[5][idx]) + (lds[6][idx] + lds[7][idx])) +
                   bih[H_ + jg] + bhh[H_ + jg];
        float gi_n = ((lds[8][idx] + lds[9][idx]) +
                      (lds[10][idx] + lds[11][idx])) + bih[2 * H_ + jg];
        float gh_n = ((lds[12][idx] + lds[13][idx]) +
                      (lds[14][idx] + lds[15][idx])) + bhh[2 * H_ + jg];
        float r_ = sigm(pr), z_ = sigm(pz);
        float n_ = tanhf(gi_n + r_ * gh_n);
        float ho = h_f32[bg * H_ + jg];   // own element (same thread wrote it)
        float hn = (1.f - z_) * n_ + z_ * ho;
        h_f32[bg * H_ + jg] = hn;
        publish_h(h0w, bg * H_ + jg, hn);
      }
    }
    group_barrier(flags, group_base, my_wg, 3 * t + 1, tid);

    // ---- P2: T = tanh(h@owW.T + owb); sig partials (fp64); y ----
    const short* hc = h_pl + wr * BH + hrow;
    if (wid < 3) {
      DECL6(qt);
      for (int kc = wid; kc < H_ / 16; kc += 3) {
        LOADA_C(a0v, a1v, a2v, hc, HN, kc);
        CHUNK6(qt, a0v, a1v, a2v, ow_p, OWWN, kc);
      }
      WRITE_TILE(lds[wid], SUM6(qt, r));
    }
    __syncthreads();
    for (int idx = tid; idx < 1024; idx += 768) {
      float s3 = lds[0][idx] + lds[1][idx] + lds[2][idx] +
                 owb[js * 32 + (idx & 31)];
      lds[0][idx] = tanhf(s3);
    }
    __syncthreads();
    if (tid < 32) {
      double sv = 0.0;
#pragma unroll 8
      for (int j = 0; j < 32; ++j)
        sv += (double)lds[0][tid * 32 + j] * (double)ovW[js * 32 + j];
      sig_part[(size_t)(t * 32 + js) * B_ + m * 32 + tid] = sv;
    }
    __syncthreads();
    if (js < 16 && wid < 3) {
      DECL6(qy);
      for (int kc = wid; kc < H_ / 16; kc += 3) {
        LOADA_C(a0v, a1v, a2v, hc, HN, kc);
        CHUNK6(qy, a0v, a1v, a2v, outw_p, OUTWN, kc);
      }
      WRITE_TILE(lds[wid], SUM6(qy, r));
    }
    __syncthreads();
    if (js < 16) {
      for (int idx = tid; idx < 1024; idx += 768) {
        const int bl = idx >> 5, j = idx & 31;
        const int d = js * 32 + j;
        float v = lds[0][idx] + lds[1][idx] + lds[2][idx] + outb[d];
        out[(size_t)(m * 32 + bl) * (TRGL * DIM) + (size_t)t * DIM + d] = v;
      }
    }
    group_barrier(flags, group_base, my_wg, 3 * t + 2, tid);

    // ---- P3: pt (fp64), alpha, context (one WG per batch) ----
    {
      double sigv = (double)ovb[0];
      for (int p = 0; p < 32; ++p)  // fixed order: deterministic
        sigv += load_c8d(&sig_part[(size_t)(t * 32 + p) * B_ + b3]);
      const double ptv = 487.0 / (1.0 + exp(-sigv)) + 6.0;
      const int center = (int)ptv;  // floor (pt > 0)
      const int row0 = center - DW; // in [0, 487]
      const float ptf = (float)ptv;
      const float* s_vec = h_f32 + b3 * H_;
      if (wid < 3) {
        for (int w = wid; w < WIN; w += 3) {
          const float* ew =
              enc_w + ((size_t)b3 * SRCL + row0 + w) * H_ + lane * 16;
          float part = 0.f;
#pragma unroll
          for (int i = 0; i < 16; ++i)
            part += ew[i] * load_c4f(&s_vec[lane * 16 + i]);
#pragma unroll
          for (int off = 32; off; off >>= 1) part += __shfl_xor(part, off, 64);
          if (lane == 0) ah13[w] = part;
        }
      }
      __syncthreads();
      if (tid == 0) {
        float v[WIN], mx = -1e30f;
#pragma unroll
        for (int w = 0; w < WIN; ++w) {
          const float dd = (float)(row0 + w) - ptf;
          v[w] = ah13[w] * expf(-(dd * dd) / 18.f);  // 2*sigma^2 = 18
          mx = fmaxf(mx, v[w]);
        }
        float ssum = 0.f;
#pragma unroll
        for (int w = 0; w < WIN; ++w) { v[w] = expf(v[w] - mx); ssum += v[w]; }
        const float inv = 1.f / ssum;
#pragma unroll
        for (int w = 0; w < WIN; ++w) al13[w] = v[w] * inv;
      }
      __syncthreads();
      for (int hh = tid; hh < H_; hh += 768) {
        const float* ewb = enc_w + ((size_t)b3 * SRCL + row0) * H_ + hh;
        float acc = 0.f;
#pragma unroll
        for (int w = 0; w < WIN; ++w) acc += al13[w] * ewb[(size_t)w * H_];
        short s0 = f2bf(acc);
        float rr = acc - bf2f(s0);
        short s1 = f2bf(rr);
        c_pl[b3 * H_ + hh] = s0;
        c_pl[CN + b3 * H_ + hh] = s1;
        c_pl[2 * CN + b3 * H_ + hh] = f2bf(rr - bf2f(s1));
      }
    }
    group_barrier(flags, group_base, my_wg, 3 * t + 3, tid);
  }
}

extern "C" void kernel_launch(void* const* d_in, const int* in_sizes, int n_in,
                              void* d_out, int out_size, void* d_ws,
                              size_t ws_size, hipStream_t stream) {
  (void)in_sizes; (void)n_in; (void)out_size; (void)ws_size;

  const float* src     = (const float*)d_in[0];
  const float* trg     = (const float*)d_in[1];
  const float* enc_Wih = (const float*)d_in[2];
  const float* enc_Whh = (const float*)d_in[3];
  const float* enc_bih = (const float*)d_in[4];
  const float* enc_bhh = (const float*)d_in[5];
  const float* dec_Wih = (const float*)d_in[6];
  const float* dec_Whh = (const float*)d_in[7];
  const float* dec_bih = (const float*)d_in[8];
  const float* dec_bhh = (const float*)d_in[9];
  const float* out_W   = (const float*)d_in[10];
  const float* out_b   = (const float*)d_in[11];
  const float* ow_W    = (const float*)d_in[12];
  const float* ow_b    = (const float*)d_in[13];
  const float* ov_W    = (const float*)d_in[14];
  const float* ov_b    = (const float*)d_in[15];
  const float* attn_W  = (const float*)d_in[16];
  const float* attn_b  = (const float*)d_in[17];

  char* ws = (char*)d_ws;
  size_t off = 0;
  auto take = [&](size_t bytes) {
    size_t o = off;
    off += (bytes + 255) & ~(size_t)255;
    return o;
  };

  // --- zeroed state region ---
  float* h_f32   = (float*)(ws + take(BH * 4));
  short* h_pl    = (short*)(ws + take((size_t)3 * HN * 2));
  short* c_pl    = (short*)(ws + take((size_t)3 * CN * 2));
  int*   flags_e = (int*)(ws + take(64 * 4));
  int*   flags_d = (int*)(ws + take(64 * 4));
  const size_t zero_bytes = off;

  // --- non-zeroed ---
  double* sig_part = (double*)(ws + take((size_t)TRGL * 32 * B_ * 8));
  short* pWihE = (short*)(ws + take((size_t)3 * EWIHN * 2));
  short* pWhhE = (short*)(ws + take((size_t)3 * EWHHN * 2));
  short* pWihD = (short*)(ws + take((size_t)3 * DWIHN * 2));
  short* pWhhD = (short*)(ws + take((size_t)3 * DWHHN * 2));
  short* pOutW = (short*)(ws + take((size_t)3 * OUTWN * 2));
  short* pOwW  = (short*)(ws + take((size_t)3 * OWWN * 2));
  short* pAtW  = (short*)(ws + take((size_t)3 * ATWN * 2));
  float* enc_w = (float*)(ws + take((size_t)B_ * SRCL * H_ * 4));

  hipMemsetAsync(ws, 0, zero_bytes, stream);

  auto split = [&](const float* in, short* outp, int n) {
    split3_kernel<<<dim3((n + 255) / 256), dim3(256), 0, stream>>>(in, outp, n);
  };
  split(enc_Wih, pWihE, EWIHN);
  split(enc_Whh, pWhhE, EWHHN);
  split(dec_Wih, pWihD, DWIHN);
  split(dec_Whh, pWhhD, DWHHN);
  split(out_W,  pOutW, OUTWN);
  split(ow_W,   pOwW,  OWWN);
  split(attn_W, pAtW,  ATWN);

  enc_kernel<<<dim3(64), dim3(768), 0, stream>>>(
      src, pWihE, pWhhE, enc_bih, enc_bhh, pAtW, attn_b, h_f32, h_pl, enc_w,
      flags_e);

  dec_kernel<<<dim3(64), dim3(768), 0, stream>>>(
      trg, pWihD, pWhhD, dec_bih, dec_bhh, pOutW, out_b, pOwW, ow_b, ov_W,
      ov_b, enc_w, h_f32, h_pl, c_pl, sig_part, flags_d, (float*)d_out);
}

// Round 4
// 56856.696 us; speedup vs baseline: 1.0074x; 1.0074x over previous
//
#include <hip/hip_runtime.h>

// ---------------------------------------------------------------------------
// Seq2seq GRU enc (500) -> local attn -> GRU dec (64). Inputs/outputs fp32.
// Precision: bf16x3 operand splits (6 MFMA chains) => fp32-true matmuls;
// sig->pt path fp64 (pt floor needs sig err < ~2e-7).
//
// R4: kill the per-step buffer_wbl2. R3 diagnosis: step time (86us) was
// invariant to 4x wave count => serialized fixed cost per barrier = the
// RELEASE agent flag store's buffer_wbl2 (full 4MiB L2 dirty walk, 8 WGs/XCD
// serialized in TCC ~= 80us/step). Now: producers write cross-WG state with
// RELAXED agent sc1 write-through stores (complete at LLC; vmcnt retires at
// coherence point); barrier = per-wave vmcnt drain + syncthreads + RELAXED
// flag store + relaxed poll + workgroup fence. Zero cache-maintenance ops.
// Consumers keep R3's relaxed sc1 loads. Weights/enc_w/out plain (cross-
// kernel only). enc h_f32 plain (WG-private); dec h_f32 via sc1 both ways.
// All arithmetic bit-identical to R3 (absmax 0.00390625).
// ---------------------------------------------------------------------------

#define B_    64
#define SRCL  500
#define TRGL  64
#define DIM   512
#define H_    1024
#define WIN   13
#define DW    6

// plane strides (elements) of the bf16x3 weight splits
#define EWIHN 1572864   // 3H*DIM
#define EWHHN 3145728   // 3H*H
#define DWIHN 4718592   // 3H*(DIM+H)
#define DWHHN 3145728
#define OUTWN 524288    // DIM*H
#define OWWN  1048576   // H*H
#define ATWN  1048576
#define BH    (B_ * H_)
#define HN    (2 * BH)  // h plane stride (2 slots)
#define CN    BH        // c plane stride

typedef __attribute__((ext_vector_type(8)))  short short8;
typedef __attribute__((ext_vector_type(16))) float floatx16;

#define MFMA(a, b, c) __builtin_amdgcn_mfma_f32_32x32x16_bf16((a), (b), (c), 0, 0, 0)

__device__ __forceinline__ float bf2f(short s) {
  union { unsigned int u; float f; } v;
  v.u = ((unsigned int)(unsigned short)s) << 16;
  return v.f;
}
__device__ __forceinline__ short f2bf(float f) {
  union { float f; unsigned int u; } v;
  v.f = f;
  unsigned int u = v.u;
  u = (u + 0x7fffu + ((u >> 16) & 1u)) >> 16;  // RNE
  return (short)u;
}
__device__ __forceinline__ floatx16 zero16() {
  floatx16 z;
#pragma unroll
  for (int i = 0; i < 16; ++i) z[i] = 0.f;
  return z;
}
__device__ __forceinline__ float sigm(float x) { return 1.f / (1.f + expf(-x)); }

// ---- coherent (agent-scope sc1, relaxed) loads: read at LLC, no inv ----
__device__ __forceinline__ short8 load_c16(const short* p) {
  unsigned long long lo = __hip_atomic_load(
      (const unsigned long long*)p, __ATOMIC_RELAXED, __HIP_MEMORY_SCOPE_AGENT);
  unsigned long long hi = __hip_atomic_load(
      (const unsigned long long*)(p + 4), __ATOMIC_RELAXED,
      __HIP_MEMORY_SCOPE_AGENT);
  union { unsigned long long u[2]; short8 s; } x;
  x.u[0] = lo; x.u[1] = hi;
  return x.s;
}
__device__ __forceinline__ float load_c4f(const float* p) {
  unsigned int u = __hip_atomic_load((const unsigned int*)p, __ATOMIC_RELAXED,
                                     __HIP_MEMORY_SCOPE_AGENT);
  union { unsigned int u; float f; } x;
  x.u = u;
  return x.f;
}
__device__ __forceinline__ double load_c8d(const double* p) {
  unsigned long long u = __hip_atomic_load(
      (const unsigned long long*)p, __ATOMIC_RELAXED, __HIP_MEMORY_SCOPE_AGENT);
  union { unsigned long long u; double d; } x;
  x.u = u;
  return x.d;
}

// ---- coherent (agent-scope sc1, relaxed) write-through stores ----
__device__ __forceinline__ void store_c2(short* p, short v) {
  __hip_atomic_store((unsigned short*)p, (unsigned short)v, __ATOMIC_RELAXED,
                     __HIP_MEMORY_SCOPE_AGENT);
}
__device__ __forceinline__ void store_c4(float* p, float v) {
  __hip_atomic_store((unsigned int*)p, __float_as_uint(v), __ATOMIC_RELAXED,
                     __HIP_MEMORY_SCOPE_AGENT);
}
__device__ __forceinline__ void store_c8(double* p, double v) {
  union { double d; unsigned long long u; } x;
  x.d = v;
  __hip_atomic_store((unsigned long long*)p, x.u, __ATOMIC_RELAXED,
                     __HIP_MEMORY_SCOPE_AGENT);
}

// 8 fp32 -> 3 bf16 planes (register split; v-s0 exact in fp32)
__device__ __forceinline__ void split8(const float* p, short8& a0, short8& a1,
                                       short8& a2) {
#pragma unroll
  for (int j = 0; j < 8; ++j) {
    float v = p[j];
    short s0 = f2bf(v);
    float r = v - bf2f(s0);
    short s1 = f2bf(r);
    r -= bf2f(s1);
    a0[j] = s0; a1[j] = s1; a2[j] = f2bf(r);
  }
}

// publish h as 3 bf16 planes via sc1 write-through stores
__device__ __forceinline__ void publish_h(short* hw, int base, float hn) {
  short s0 = f2bf(hn);
  float rr = hn - bf2f(s0);
  short s1 = f2bf(rr);
  store_c2(hw + base, s0);
  store_c2(hw + HN + base, s1);
  store_c2(hw + 2 * HN + base, f2bf(rr - bf2f(s1)));
}

#define DECL6(P) floatx16 P##00 = zero16(), P##01 = zero16(), \
                          P##10 = zero16(), P##2 = zero16();
#define SUM6(P, r) (P##00[r] + P##01[r] + P##10[r] + P##2[r])

// plain-load A (weights / read-only inputs)
#define LOADA(a0v, a1v, a2v, ap, AN, kc)                                    \
  const short8 a0v = *(const short8*)((ap) + (size_t)(kc)*16);              \
  const short8 a1v = *(const short8*)((ap) + (size_t)(AN) + (size_t)(kc)*16); \
  const short8 a2v = *(const short8*)((ap) + 2*(size_t)(AN) + (size_t)(kc)*16);

// coherent-load A (cross-WG mutable state: h planes, c planes)
#define LOADA_C(a0v, a1v, a2v, ap, AN, kc)                                  \
  const short8 a0v = load_c16((ap) + (size_t)(kc)*16);                      \
  const short8 a1v = load_c16((ap) + (size_t)(AN) + (size_t)(kc)*16);       \
  const short8 a2v = load_c16((ap) + 2*(size_t)(AN) + (size_t)(kc)*16);

#define CHUNK6(P, a0v, a1v, a2v, bp, BN, kc)                                 \
  {                                                                          \
    const short8 b0v = *(const short8*)((bp) + (size_t)(kc)*16);             \
    const short8 b1v = *(const short8*)((bp) + (size_t)(BN) + (size_t)(kc)*16); \
    const short8 b2v = *(const short8*)((bp) + 2*(size_t)(BN) + (size_t)(kc)*16); \
    P##00 = MFMA(a0v, b0v, P##00);                                           \
    P##01 = MFMA(a0v, b1v, P##01);                                           \
    P##10 = MFMA(a1v, b0v, P##10);                                           \
    P##2  = MFMA(a0v, b2v, P##2);                                            \
    P##2  = MFMA(a1v, b1v, P##2);                                            \
    P##2  = MFMA(a2v, b0v, P##2);                                            \
  }

// C-fragment scatter
#define WRITE_TILE(dst, EXPR)                                        \
  do {                                                               \
    _Pragma("unroll") for (int r = 0; r < 16; ++r) {                 \
      int row_ = (r & 3) + 8 * (r >> 2) + 4 * (lane >> 5);           \
      (dst)[row_ * 32 + ra] = (EXPR);                                \
    }                                                                \
  } while (0)

// R4 barrier: NO release, NO cache-maintenance ops.
// Each wave drains its own sc1 stores (vmcnt retires at the LLC coherence
// point for write-through stores) -> syncthreads -> tid0 RELAXED sc1 flag
// store -> relaxed sc1 poll -> workgroup-scope acquire fence (compiler/
// waitcnt ordering only) -> syncthreads.
__device__ __forceinline__ void group_barrier(int* flags, int group_base,
                                              int my_wg, int epoch, int tid) {
  asm volatile("s_waitcnt vmcnt(0) lgkmcnt(0)" ::: "memory");
  __syncthreads();
  if (tid == 0)
    __hip_atomic_store(&flags[my_wg], epoch, __ATOMIC_RELAXED,
                       __HIP_MEMORY_SCOPE_AGENT);
  const int idx = group_base + (tid & 31);
  while (__hip_atomic_load(&flags[idx], __ATOMIC_RELAXED,
                           __HIP_MEMORY_SCOPE_AGENT) < epoch)
    __builtin_amdgcn_s_sleep(1);
  __builtin_amdgcn_fence(__ATOMIC_ACQUIRE, "workgroup");
  __syncthreads();
}

// fp32 -> 3 bf16 planes (weights, done once)
__global__ void split3_kernel(const float* __restrict__ in,
                              short* __restrict__ out, int n) {
  const int i = blockIdx.x * 256 + threadIdx.x;
  if (i >= n) return;
  float v = in[i];
  short s0 = f2bf(v);
  float r = v - bf2f(s0);
  short s1 = f2bf(r);
  r -= bf2f(s1);
  out[i] = s0;
  out[n + i] = s1;
  out[2 * n + i] = f2bf(r);
}

// ---------------------------------------------------------------------------
// Encoder + fused attn transform (enc_w row t-1 each iter, wid<3, kc mod 3).
// GRU: 12 waves, wave=(gate g, K-quarter q).
// ---------------------------------------------------------------------------
__global__ __launch_bounds__(768) void enc_kernel(
    const float* __restrict__ src, const short* __restrict__ Wih,
    const short* __restrict__ Whh, const float* __restrict__ bih,
    const float* __restrict__ bhh, const short* __restrict__ attnW,
    const float* __restrict__ attn_b, float* __restrict__ h_f32,
    short* __restrict__ h_pl, float* __restrict__ enc_w,
    int* __restrict__ flags) {
  const int tid  = threadIdx.x;
  const int lane = tid & 63;
  const int wid  = tid >> 6;   // 0..11
  const int g    = wid >> 2;   // gate 0..2
  const int q    = wid & 3;    // K-quarter
  const int m    = blockIdx.x >> 5;
  const int js   = blockIdx.x & 31;
  const int ra   = lane & 31;
  const int koff = (lane >> 5) * 8;

  __shared__ float lds[16][1024];

  const int nrow = g * H_ + js * 32 + ra;
  const short* wih_p = Wih + (size_t)nrow * DIM + koff;
  const short* whh_p = Whh + (size_t)nrow * H_ + koff;
  const short* atw_p = attnW + (size_t)(js * 32 + ra) * H_ + koff;
  const float* src_p = src + (size_t)(m * 32 + ra) * (SRCL * DIM) + koff;
  const int hrow = (m * 32 + ra) * H_ + koff;

  const int group_base = m * 32;
  const int my_wg = blockIdx.x;

  for (int t = 0; t < SRCL; ++t) {
    const short* hp = h_pl + (t & 1) * BH + hrow;

    // ---- fused attn: enc_w row t-1 from h slot (t&1); wid<3, kc mod 3 ----
    if (t > 0) {
      if (wid < 3) {
        DECL6(qa);
        for (int kc = wid; kc < H_ / 16; kc += 3) {
          LOADA_C(a0v, a1v, a2v, hp, HN, kc);
          CHUNK6(qa, a0v, a1v, a2v, atw_p, ATWN, kc);
        }
        WRITE_TILE(lds[wid], SUM6(qa, r));
      }
      __syncthreads();
      for (int idx = tid; idx < 1024; idx += 768) {
        const int bl = idx >> 5, j = idx & 31;
        float v = lds[0][idx] + lds[1][idx] + lds[2][idx] + attn_b[js * 32 + j];
        enc_w[((size_t)(m * 32 + bl) * SRCL + (t - 1)) * H_ + js * 32 + j] = v;
      }
      __syncthreads();
    }

    // ---- GRU matmuls, 4-way K-split per gate ----
    const float* xp = src_p + (size_t)t * DIM;
    if (g < 2) {
      DECL6(qa);
#pragma unroll 4
      for (int kc = q * 8; kc < q * 8 + 8; ++kc) {
        short8 a0v, a1v, a2v;
        split8(xp + kc * 16, a0v, a1v, a2v);
        CHUNK6(qa, a0v, a1v, a2v, wih_p, EWIHN, kc);
      }
#pragma unroll 4
      for (int kc = q * 16; kc < q * 16 + 16; ++kc) {
        LOADA_C(a0v, a1v, a2v, hp, HN, kc);
        CHUNK6(qa, a0v, a1v, a2v, whh_p, EWHHN, kc);
      }
      WRITE_TILE(lds[wid], SUM6(qa, r));
    } else {
      {
        DECL6(qa);
#pragma unroll 4
        for (int kc = q * 8; kc < q * 8 + 8; ++kc) {
          short8 a0v, a1v, a2v;
          split8(xp + kc * 16, a0v, a1v, a2v);
          CHUNK6(qa, a0v, a1v, a2v, wih_p, EWIHN, kc);
        }
        WRITE_TILE(lds[8 + q], SUM6(qa, r));
      }
      {
        DECL6(qb);
#pragma unroll 4
        for (int kc = q * 16; kc < q * 16 + 16; ++kc) {
          LOADA_C(a0v, a1v, a2v, hp, HN, kc);
          CHUNK6(qb, a0v, a1v, a2v, whh_p, EWHHN, kc);
        }
        WRITE_TILE(lds[12 + q], SUM6(qb, r));
      }
    }
    __syncthreads();

    // ---- elementwise + publish h (sc1 write-through stores) ----
    short* h0w = h_pl + ((t + 1) & 1) * BH;
    for (int idx = tid; idx < 1024; idx += 768) {
      const int bl = idx >> 5, j = idx & 31;
      const int jg = js * 32 + j;
      const int bg = m * 32 + bl;
      float pr = ((lds[0][idx] + lds[1][idx]) + (lds[2][idx] + lds[3][idx])) +
                 bih[jg] + bhh[jg];
      float pz = ((lds[4][idx] + lds[5][idx]) + (lds[6][idx] + lds[7][idx])) +
                 bih[H_ + jg] + bhh[H_ + jg];
      float gi_n = ((lds[8][idx] + lds[9][idx]) +
                    (lds[10][idx] + lds[11][idx])) + bih[2 * H_ + jg];
      float gh_n = ((lds[12][idx] + lds[13][idx]) +
                    (lds[14][idx] + lds[15][idx])) + bhh[2 * H_ + jg];
      float r_ = sigm(pr), z_ = sigm(pz);
      float n_ = tanhf(gi_n + r_ * gh_n);
      float ho = h_f32[bg * H_ + jg];
      float hn = (1.f - z_) * n_ + z_ * ho;
      h_f32[bg * H_ + jg] = hn;            // enc-private, plain
      publish_h(h0w, bg * H_ + jg, hn);
    }
    group_barrier(flags, group_base, my_wg, t + 1, tid);
  }

  // ---- final fused attn: enc_w row 499 from h slot 0 ----
  {
    const short* hp = h_pl + 0 * BH + hrow;
    if (wid < 3) {
      DECL6(qa);
      for (int kc = wid; kc < H_ / 16; kc += 3) {
        LOADA_C(a0v, a1v, a2v, hp, HN, kc);
        CHUNK6(qa, a0v, a1v, a2v, atw_p, ATWN, kc);
      }
      WRITE_TILE(lds[wid], SUM6(qa, r));
    }
    __syncthreads();
    for (int idx = tid; idx < 1024; idx += 768) {
      const int bl = idx >> 5, j = idx & 31;
      float v = lds[0][idx] + lds[1][idx] + lds[2][idx] + attn_b[js * 32 + j];
      enc_w[((size_t)(m * 32 + bl) * SRCL + (SRCL - 1)) * H_ + js * 32 + j] = v;
    }
  }
}

// ---------------------------------------------------------------------------
// Decoder: 64 WGs x 768 thr, 3 phases per step.
// ---------------------------------------------------------------------------
__global__ __launch_bounds__(768) void dec_kernel(
    const float* __restrict__ trg, const short* __restrict__ Wih,
    const short* __restrict__ Whh, const float* __restrict__ bih,
    const float* __restrict__ bhh, const short* __restrict__ outW,
    const float* __restrict__ outb, const short* __restrict__ owW,
    const float* __restrict__ owb, const float* __restrict__ ovW,
    const float* __restrict__ ovb, const float* __restrict__ enc_w,
    float* __restrict__ h_f32, short* __restrict__ h_pl,
    short* __restrict__ c_pl, double* __restrict__ sig_part,
    int* __restrict__ flags, float* __restrict__ out) {
  const int tid  = threadIdx.x;
  const int lane = tid & 63;
  const int wid  = tid >> 6;   // 0..11
  const int g    = wid >> 2;
  const int q    = wid & 3;
  const int m    = blockIdx.x >> 5;
  const int js   = blockIdx.x & 31;
  const int ra   = lane & 31;
  const int koff = (lane >> 5) * 8;

  __shared__ float lds[16][1024];
  __shared__ float al13[WIN];
  __shared__ float ah13[WIN];

  const int nrow = g * H_ + js * 32 + ra;
  const short* wx_p = Wih + (size_t)nrow * (DIM + H_) + koff;  // x cols
  const short* wc_p = wx_p + DIM;                              // c cols
  const short* wh_p = Whh + (size_t)nrow * H_ + koff;
  const float* trg_p = trg + (size_t)(m * 32 + ra) * (TRGL * DIM) + koff;
  const int hrow = (m * 32 + ra) * H_ + koff;
  const short* cp = c_pl + hrow;
  const short* ow_p = owW + (size_t)(js * 32 + ra) * H_ + koff;
  const short* outw_p = outW + (size_t)((js & 15) * 32 + ra) * H_ + koff;

  const int group_base = m * 32;
  const int my_wg = blockIdx.x;
  const int b3 = blockIdx.x;  // P3: WG <-> batch

  for (int t = 0; t < TRGL; ++t) {
    const int rd = t & 1, wr = (t + 1) & 1;
    const short* hp = h_pl + rd * BH + hrow;

    // ---- P1: GRU, 4-way K-split. gi over [x_t, c]; gh over h ----
    if (g < 2) {
      DECL6(qa);
      if (t > 0) {
        const float* xp = trg_p + (size_t)(t - 1) * DIM;
#pragma unroll 4
        for (int kc = q * 8; kc < q * 8 + 8; ++kc) {
          short8 a0v, a1v, a2v;
          split8(xp + kc * 16, a0v, a1v, a2v);
          CHUNK6(qa, a0v, a1v, a2v, wx_p, DWIHN, kc);
        }
      }
#pragma unroll 4
      for (int kc = q * 16; kc < q * 16 + 16; ++kc) {
        LOADA_C(a0v, a1v, a2v, cp, CN, kc);
        CHUNK6(qa, a0v, a1v, a2v, wc_p, DWIHN, kc);
      }
#pragma unroll 4
      for (int kc = q * 16; kc < q * 16 + 16; ++kc) {
        LOADA_C(a0v, a1v, a2v, hp, HN, kc);
        CHUNK6(qa, a0v, a1v, a2v, wh_p, DWHHN, kc);
      }
      WRITE_TILE(lds[wid], SUM6(qa, r));
    } else {
      {
        DECL6(qa);
        if (t > 0) {
          const float* xp = trg_p + (size_t)(t - 1) * DIM;
#pragma unroll 4
          for (int kc = q * 8; kc < q * 8 + 8; ++kc) {
            short8 a0v, a1v, a2v;
            split8(xp + kc * 16, a0v, a1v, a2v);
            CHUNK6(qa, a0v, a1v, a2v, wx_p, DWIHN, kc);
          }
        }
#pragma unroll 4
        for (int kc = q * 16; kc < q * 16 + 16; ++kc) {
          LOADA_C(a0v, a1v, a2v, cp, CN, kc);
          CHUNK6(qa, a0v, a1v, a2v, wc_p, DWIHN, kc);
        }
        WRITE_TILE(lds[8 + q], SUM6(qa, r));
      }
      {
        DECL6(qb);
#pragma unroll 4
        for (int kc = q * 16; kc < q * 16 + 16; ++kc) {
          LOADA_C(a0v, a1v, a2v, hp, HN, kc);
          CHUNK6(qb, a0v, a1v, a2v, wh_p, DWHHN, kc);
        }
        WRITE_TILE(lds[12 + q], SUM6(qb, r));
      }
    }
    __syncthreads();
    {
      short* h0w = h_pl + wr * BH;
      for (int idx = tid; idx < 1024; idx += 768) {
        const int bl = idx >> 5, j = idx & 31;
        const int jg = js * 32 + j;
        const int bg = m * 32 + bl;
        float pr = ((lds[0][idx] + lds[1][idx]) + (lds[2][idx] + lds[3][idx])) +
                   bih[jg] + bhh[jg];
        float pz = ((lds[4][idx] + lds[5][idx]) + (lds[6][idx] + lds[7][idx])) +
                   bih[H_ + jg] + bhh[H_ + jg];
        float gi_n = ((lds[8][idx] + lds[9][idx]) +
                      (lds[10][idx] + lds[11][idx])) + bih[2 * H_ + jg];
        float gh_n = ((lds[12][idx] + lds[13][idx]) +
                      (lds[14][idx] + lds[15][idx])) + bhh[2 * H_ + jg];
        float r_ = sigm(pr), z_ = sigm(pz);
        float n_ = tanhf(gi_n + r_ * gh_n);
        float ho = load_c4f(&h_f32[bg * H_ + jg]);  // sc1 (was sc1-written)
        float hn = (1.f - z_) * n_ + z_ * ho;
        store_c4(&h_f32[bg * H_ + jg], hn);         // read by P3 cross-WG
        publish_h(h0w, bg * H_ + jg, hn);
      }
    }
    group_barrier(flags, group_base, my_wg, 3 * t + 1, tid);

    // ---- P2: T = tanh(h@owW.T + owb); sig partials (fp64); y ----
    const short* hc = h_pl + wr * BH + hrow;
    if (wid < 3) {
      DECL6(qt);
      for (int kc = wid; kc < H_ / 16; kc += 3) {
        LOADA_C(a0v, a1v, a2v, hc, HN, kc);
        CHUNK6(qt, a0v, a1v, a2v, ow_p, OWWN, kc);
      }
      WRITE_TILE(lds[wid], SUM6(qt, r));
    }
    __syncthreads();
    for (int idx = tid; idx < 1024; idx += 768) {
      float s3 = lds[0][idx] + lds[1][idx] + lds[2][idx] +
                 owb[js * 32 + (idx & 31)];
      lds[0][idx] = tanhf(s3);
    }
    __syncthreads();
    if (tid < 32) {
      double sv = 0.0;
#pragma unroll 8
      for (int j = 0; j < 32; ++j)
        sv += (double)lds[0][tid * 32 + j] * (double)ovW[js * 32 + j];
      store_c8(&sig_part[(size_t)(t * 32 + js) * B_ + m * 32 + tid], sv);
    }
    __syncthreads();
    if (js < 16 && wid < 3) {
      DECL6(qy);
      for (int kc = wid; kc < H_ / 16; kc += 3) {
        LOADA_C(a0v, a1v, a2v, hc, HN, kc);
        CHUNK6(qy, a0v, a1v, a2v, outw_p, OUTWN, kc);
      }
      WRITE_TILE(lds[wid], SUM6(qy, r));
    }
    __syncthreads();
    if (js < 16) {
      for (int idx = tid; idx < 1024; idx += 768) {
        const int bl = idx >> 5, j = idx & 31;
        const int d = js * 32 + j;
        float v = lds[0][idx] + lds[1][idx] + lds[2][idx] + outb[d];
        out[(size_t)(m * 32 + bl) * (TRGL * DIM) + (size_t)t * DIM + d] = v;
      }
    }
    group_barrier(flags, group_base, my_wg, 3 * t + 2, tid);

    // ---- P3: pt (fp64), alpha, context (one WG per batch) ----
    {
      double sigv = (double)ovb[0];
      for (int p = 0; p < 32; ++p)  // fixed order: deterministic
        sigv += load_c8d(&sig_part[(size_t)(t * 32 + p) * B_ + b3]);
      const double ptv = 487.0 / (1.0 + exp(-sigv)) + 6.0;
      const int center = (int)ptv;  // floor (pt > 0)
      const int row0 = center - DW; // in [0, 487]
      const float ptf = (float)ptv;
      const float* s_vec = h_f32 + b3 * H_;
      if (wid < 3) {
        for (int w = wid; w < WIN; w += 3) {
          const float* ew =
              enc_w + ((size_t)b3 * SRCL + row0 + w) * H_ + lane * 16;
          float part = 0.f;
#pragma unroll
          for (int i = 0; i < 16; ++i)
            part += ew[i] * load_c4f(&s_vec[lane * 16 + i]);
#pragma unroll
          for (int off = 32; off; off >>= 1) part += __shfl_xor(part, off, 64);
          if (lane == 0) ah13[w] = part;
        }
      }
      __syncthreads();
      if (tid == 0) {
        float v[WIN], mx = -1e30f;
#pragma unroll
        for (int w = 0; w < WIN; ++w) {
          const float dd = (float)(row0 + w) - ptf;
          v[w] = ah13[w] * expf(-(dd * dd) / 18.f);  // 2*sigma^2 = 18
          mx = fmaxf(mx, v[w]);
        }
        float ssum = 0.f;
#pragma unroll
        for (int w = 0; w < WIN; ++w) { v[w] = expf(v[w] - mx); ssum += v[w]; }
        const float inv = 1.f / ssum;
#pragma unroll
        for (int w = 0; w < WIN; ++w) al13[w] = v[w] * inv;
      }
      __syncthreads();
      for (int hh = tid; hh < H_; hh += 768) {
        const float* ewb = enc_w + ((size_t)b3 * SRCL + row0) * H_ + hh;
        float acc = 0.f;
#pragma unroll
        for (int w = 0; w < WIN; ++w) acc += al13[w] * ewb[(size_t)w * H_];
        short s0 = f2bf(acc);
        float rr = acc - bf2f(s0);
        short s1 = f2bf(rr);
        store_c2(&c_pl[b3 * H_ + hh], s0);
        store_c2(&c_pl[CN + b3 * H_ + hh], s1);
        store_c2(&c_pl[2 * CN + b3 * H_ + hh], f2bf(rr - bf2f(s1)));
      }
    }
    group_barrier(flags, group_base, my_wg, 3 * t + 3, tid);
  }
}

extern "C" void kernel_launch(void* const* d_in, const int* in_sizes, int n_in,
                              void* d_out, int out_size, void* d_ws,
                              size_t ws_size, hipStream_t stream) {
  (void)in_sizes; (void)n_in; (void)out_size; (void)ws_size;

  const float* src     = (const float*)d_in[0];
  const float* trg     = (const float*)d_in[1];
  const float* enc_Wih = (const float*)d_in[2];
  const float* enc_Whh = (const float*)d_in[3];
  const float* enc_bih = (const float*)d_in[4];
  const float* enc_bhh = (const float*)d_in[5];
  const float* dec_Wih = (const float*)d_in[6];
  const float* dec_Whh = (const float*)d_in[7];
  const float* dec_bih = (const float*)d_in[8];
  const float* dec_bhh = (const float*)d_in[9];
  const float* out_W   = (const float*)d_in[10];
  const float* out_b   = (const float*)d_in[11];
  const float* ow_W    = (const float*)d_in[12];
  const float* ow_b    = (const float*)d_in[13];
  const float* ov_W    = (const float*)d_in[14];
  const float* ov_b    = (const float*)d_in[15];
  const float* attn_W  = (const float*)d_in[16];
  const float* attn_b  = (const float*)d_in[17];

  char* ws = (char*)d_ws;
  size_t off = 0;
  auto take = [&](size_t bytes) {
    size_t o = off;
    off += (bytes + 255) & ~(size_t)255;
    return o;
  };

  // --- zeroed state region ---
  float* h_f32   = (float*)(ws + take(BH * 4));
  short* h_pl    = (short*)(ws + take((size_t)3 * HN * 2));
  short* c_pl    = (short*)(ws + take((size_t)3 * CN * 2));
  int*   flags_e = (int*)(ws + take(64 * 4));
  int*   flags_d = (int*)(ws + take(64 * 4));
  const size_t zero_bytes = off;

  // --- non-zeroed ---
  double* sig_part = (double*)(ws + take((size_t)TRGL * 32 * B_ * 8));
  short* pWihE = (short*)(ws + take((size_t)3 * EWIHN * 2));
  short* pWhhE = (short*)(ws + take((size_t)3 * EWHHN * 2));
  short* pWihD = (short*)(ws + take((size_t)3 * DWIHN * 2));
  short* pWhhD = (short*)(ws + take((size_t)3 * DWHHN * 2));
  short* pOutW = (short*)(ws + take((size_t)3 * OUTWN * 2));
  short* pOwW  = (short*)(ws + take((size_t)3 * OWWN * 2));
  short* pAtW  = (short*)(ws + take((size_t)3 * ATWN * 2));
  float* enc_w = (float*)(ws + take((size_t)B_ * SRCL * H_ * 4));

  hipMemsetAsync(ws, 0, zero_bytes, stream);

  auto split = [&](const float* in, short* outp, int n) {
    split3_kernel<<<dim3((n + 255) / 256), dim3(256), 0, stream>>>(in, outp, n);
  };
  split(enc_Wih, pWihE, EWIHN);
  split(enc_Whh, pWhhE, EWHHN);
  split(dec_Wih, pWihD, DWIHN);
  split(dec_Whh, pWhhD, DWHHN);
  split(out_W,  pOutW, OUTWN);
  split(ow_W,   pOwW,  OWWN);
  split(attn_W, pAtW,  ATWN);

  enc_kernel<<<dim3(64), dim3(768), 0, stream>>>(
      src, pWihE, pWhhE, enc_bih, enc_bhh, pAtW, attn_b, h_f32, h_pl, enc_w,
      flags_e);

  dec_kernel<<<dim3(64), dim3(768), 0, stream>>>(
      trg, pWihD, pWhhD, dec_bih, dec_bhh, pOutW, out_b, pOwW, ow_b, ov_W,
      ov_b, enc_w, h_f32, h_pl, c_pl, sig_part, flags_d, (float*)d_out);
}

// Round 5
// 26970.923 us; speedup vs baseline: 2.1236x; 2.1081x over previous
//
#include <hip/hip_runtime.h>

// ---------------------------------------------------------------------------
// Seq2seq GRU enc (500) -> local attn -> GRU dec (64). Inputs/outputs fp32.
// Precision: bf16x3 operand splits (6 MFMA chains) => fp32-true matmuls;
// sig->pt path fp64.
//
// R5: per-CU memory-request-cap diagnosis (step time invariant to wave count
// and to all cache-op changes => ~60cyc/vmem-instr per-CU throughput cap).
// Restructure to 256 WGs (one 32x32 tile per CU): 192 GRU gate tiles
// (m x gate x js) + 64 attn/aux tiles. 4 waves/WG, K-split 4-way (same
// grouping as R4 => bit-identical sums). Gate tiles -> gate_buf (fp32 sc1),
// 2nd barrier, 32 WGs/group do h-elementwise. blockIdx mapping co-locates
// same-js tiles on one XCD (delta bid % 8 == 0) => weights L2-resident.
// Decoder: same split, 4 phases/step (GRU tiles / h-elem / ow+out tiles /
// attn-context). Barriers: R4 style (relaxed sc1 flags, no cache ops),
// groups of 128 per batch-half.
// ---------------------------------------------------------------------------

#define B_    64
#define SRCL  500
#define TRGL  64
#define DIM   512
#define H_    1024
#define WIN   13
#define DW    6

#define EWIHN 1572864   // 3H*DIM
#define EWHHN 3145728   // 3H*H
#define DWIHN 4718592   // 3H*(DIM+H)
#define DWHHN 3145728
#define OUTWN 524288    // DIM*H
#define OWWN  1048576   // H*H
#define ATWN  1048576
#define BH    (B_ * H_)
#define HN    (2 * BH)  // h plane stride (2 slots)
#define CN    BH        // c plane stride
#define GBSTR 4096      // gate_buf per-batch-row stride (4 tiles x 1024)

typedef __attribute__((ext_vector_type(8)))  short short8;
typedef __attribute__((ext_vector_type(16))) float floatx16;

#define MFMA(a, b, c) __builtin_amdgcn_mfma_f32_32x32x16_bf16((a), (b), (c), 0, 0, 0)

__device__ __forceinline__ float bf2f(short s) {
  union { unsigned int u; float f; } v;
  v.u = ((unsigned int)(unsigned short)s) << 16;
  return v.f;
}
__device__ __forceinline__ short f2bf(float f) {
  union { float f; unsigned int u; } v;
  v.f = f;
  unsigned int u = v.u;
  u = (u + 0x7fffu + ((u >> 16) & 1u)) >> 16;  // RNE
  return (short)u;
}
__device__ __forceinline__ floatx16 zero16() {
  floatx16 z;
#pragma unroll
  for (int i = 0; i < 16; ++i) z[i] = 0.f;
  return z;
}
__device__ __forceinline__ float sigm(float x) { return 1.f / (1.f + expf(-x)); }

// ---- coherent (agent-scope sc1, relaxed) loads ----
__device__ __forceinline__ short8 load_c16(const short* p) {
  unsigned long long lo = __hip_atomic_load(
      (const unsigned long long*)p, __ATOMIC_RELAXED, __HIP_MEMORY_SCOPE_AGENT);
  unsigned long long hi = __hip_atomic_load(
      (const unsigned long long*)(p + 4), __ATOMIC_RELAXED,
      __HIP_MEMORY_SCOPE_AGENT);
  union { unsigned long long u[2]; short8 s; } x;
  x.u[0] = lo; x.u[1] = hi;
  return x.s;
}
__device__ __forceinline__ float load_c4f(const float* p) {
  unsigned int u = __hip_atomic_load((const unsigned int*)p, __ATOMIC_RELAXED,
                                     __HIP_MEMORY_SCOPE_AGENT);
  union { unsigned int u; float f; } x;
  x.u = u;
  return x.f;
}
__device__ __forceinline__ double load_c8d(const double* p) {
  unsigned long long u = __hip_atomic_load(
      (const unsigned long long*)p, __ATOMIC_RELAXED, __HIP_MEMORY_SCOPE_AGENT);
  union { unsigned long long u; double d; } x;
  x.u = u;
  return x.d;
}

// ---- coherent (agent-scope sc1, relaxed) stores ----
__device__ __forceinline__ void store_c2(short* p, short v) {
  __hip_atomic_store((unsigned short*)p, (unsigned short)v, __ATOMIC_RELAXED,
                     __HIP_MEMORY_SCOPE_AGENT);
}
__device__ __forceinline__ void store_c4(float* p, float v) {
  __hip_atomic_store((unsigned int*)p, __float_as_uint(v), __ATOMIC_RELAXED,
                     __HIP_MEMORY_SCOPE_AGENT);
}
__device__ __forceinline__ void store_c8(double* p, double v) {
  union { double d; unsigned long long u; } x;
  x.d = v;
  __hip_atomic_store((unsigned long long*)p, x.u, __ATOMIC_RELAXED,
                     __HIP_MEMORY_SCOPE_AGENT);
}

__device__ __forceinline__ void split8(const float* p, short8& a0, short8& a1,
                                       short8& a2) {
#pragma unroll
  for (int j = 0; j < 8; ++j) {
    float v = p[j];
    short s0 = f2bf(v);
    float r = v - bf2f(s0);
    short s1 = f2bf(r);
    r -= bf2f(s1);
    a0[j] = s0; a1[j] = s1; a2[j] = f2bf(r);
  }
}

__device__ __forceinline__ void publish_h(short* hw, int base, float hn) {
  short s0 = f2bf(hn);
  float rr = hn - bf2f(s0);
  short s1 = f2bf(rr);
  store_c2(hw + base, s0);
  store_c2(hw + HN + base, s1);
  store_c2(hw + 2 * HN + base, f2bf(rr - bf2f(s1)));
}

#define DECL6(P) floatx16 P##00 = zero16(), P##01 = zero16(), \
                          P##10 = zero16(), P##2 = zero16();
#define SUM6(P, r) (P##00[r] + P##01[r] + P##10[r] + P##2[r])

#define LOADA_C(a0v, a1v, a2v, ap, AN, kc)                                  \
  const short8 a0v = load_c16((ap) + (size_t)(kc)*16);                      \
  const short8 a1v = load_c16((ap) + (size_t)(AN) + (size_t)(kc)*16);       \
  const short8 a2v = load_c16((ap) + 2*(size_t)(AN) + (size_t)(kc)*16);

#define CHUNK6(P, a0v, a1v, a2v, bp, BN, kc)                                 \
  {                                                                          \
    const short8 b0v = *(const short8*)((bp) + (size_t)(kc)*16);             \
    const short8 b1v = *(const short8*)((bp) + (size_t)(BN) + (size_t)(kc)*16); \
    const short8 b2v = *(const short8*)((bp) + 2*(size_t)(BN) + (size_t)(kc)*16); \
    P##00 = MFMA(a0v, b0v, P##00);                                           \
    P##01 = MFMA(a0v, b1v, P##01);                                           \
    P##10 = MFMA(a1v, b0v, P##10);                                           \
    P##2  = MFMA(a0v, b2v, P##2);                                            \
    P##2  = MFMA(a1v, b1v, P##2);                                            \
    P##2  = MFMA(a2v, b0v, P##2);                                            \
  }

#define WRITE_TILE(dst, EXPR)                                        \
  do {                                                               \
    _Pragma("unroll") for (int r = 0; r < 16; ++r) {                 \
      int row_ = (r & 3) + 8 * (r >> 2) + 4 * (lane >> 5);           \
      (dst)[row_ * 32 + ra] = (EXPR);                                \
    }                                                                \
  } while (0)

// Barrier over 128-WG group: relaxed sc1 flags, no cache-maintenance ops.
__device__ __forceinline__ void group_barrier(int* flags, int fbase, int grp,
                                              int epoch, int tid) {
  asm volatile("s_waitcnt vmcnt(0) lgkmcnt(0)" ::: "memory");
  __syncthreads();
  if (tid == 0)
    __hip_atomic_store(&flags[fbase + grp], epoch, __ATOMIC_RELAXED,
                       __HIP_MEMORY_SCOPE_AGENT);
  if (tid < 128) {
    while (__hip_atomic_load(&flags[fbase + tid], __ATOMIC_RELAXED,
                             __HIP_MEMORY_SCOPE_AGENT) < epoch)
      __builtin_amdgcn_s_sleep(1);
  }
  __builtin_amdgcn_fence(__ATOMIC_ACQUIRE, "workgroup");
  __syncthreads();
}

__global__ void split3_kernel(const float* __restrict__ in,
                              short* __restrict__ out, int n) {
  const int i = blockIdx.x * 256 + threadIdx.x;
  if (i >= n) return;
  float v = in[i];
  short s0 = f2bf(v);
  float r = v - bf2f(s0);
  short s1 = f2bf(r);
  r -= bf2f(s1);
  out[i] = s0;
  out[n + i] = s1;
  out[2 * n + i] = f2bf(r);
}

// ---------------------------------------------------------------------------
// Encoder: 256 WGs x 256 thr. bid<192: GRU tile (mm=bid/96, g, js); else aux
// (attn tile). Group mm = 96 GRU + 32 aux WGs; flags [mm*128 + grp].
// 2 barriers/step: A after gate_buf/enc_w, B after h-elementwise.
// ---------------------------------------------------------------------------
__global__ __launch_bounds__(256) void enc_kernel(
    const float* __restrict__ src, const short* __restrict__ Wih,
    const short* __restrict__ Whh, const float* __restrict__ bih,
    const float* __restrict__ bhh, const short* __restrict__ attnW,
    const float* __restrict__ attn_b, float* __restrict__ h_f32,
    short* __restrict__ h_pl, float* __restrict__ enc_w,
    float* __restrict__ gb, int* __restrict__ flags) {
  const int tid  = threadIdx.x;
  const int lane = tid & 63;
  const int wid  = tid >> 6;   // 0..3
  const int ra   = lane & 31;
  const int koff = (lane >> 5) * 8;
  const int bid  = blockIdx.x;

  const bool isGRU = bid < 192;
  int mm, g, js, grp;
  if (isGRU) {
    mm = bid / 96; grp = bid % 96; g = grp >> 5; js = grp & 31;
  } else {
    int aux = bid - 192; mm = aux >> 5; js = aux & 31; g = 0; grp = 96 + js;
  }
  const int fbase = mm * 128;

  __shared__ float lds[8][1024];

  const int hrow = (mm * 32 + ra) * H_ + koff;
  const int nrow = g * H_ + js * 32 + ra;
  const short* wih_p = Wih + (size_t)nrow * DIM + koff;
  const short* whh_p = Whh + (size_t)nrow * H_ + koff;
  const short* atw_p = attnW + (size_t)(js * 32 + ra) * H_ + koff;
  const float* src_p = src + (size_t)(mm * 32 + ra) * (SRCL * DIM) + koff;

  int epoch = 0;
  for (int t = 0; t < SRCL; ++t) {
    const short* hp = h_pl + (t & 1) * BH + hrow;

    if (isGRU) {
      const float* xp = src_p + (size_t)t * DIM;
      if (g < 2) {
        DECL6(qa);
#pragma unroll 4
        for (int kc = wid * 8; kc < wid * 8 + 8; ++kc) {
          short8 a0v, a1v, a2v;
          split8(xp + kc * 16, a0v, a1v, a2v);
          CHUNK6(qa, a0v, a1v, a2v, wih_p, EWIHN, kc);
        }
#pragma unroll 4
        for (int kc = wid * 16; kc < wid * 16 + 16; ++kc) {
          LOADA_C(a0v, a1v, a2v, hp, HN, kc);
          CHUNK6(qa, a0v, a1v, a2v, whh_p, EWHHN, kc);
        }
        WRITE_TILE(lds[wid], SUM6(qa, r));
      } else {
        {
          DECL6(qa);
#pragma unroll 4
          for (int kc = wid * 8; kc < wid * 8 + 8; ++kc) {
            short8 a0v, a1v, a2v;
            split8(xp + kc * 16, a0v, a1v, a2v);
            CHUNK6(qa, a0v, a1v, a2v, wih_p, EWIHN, kc);
          }
          WRITE_TILE(lds[wid], SUM6(qa, r));
        }
        {
          DECL6(qb);
#pragma unroll 4
          for (int kc = wid * 16; kc < wid * 16 + 16; ++kc) {
            LOADA_C(a0v, a1v, a2v, hp, HN, kc);
            CHUNK6(qb, a0v, a1v, a2v, whh_p, EWHHN, kc);
          }
          WRITE_TILE(lds[4 + wid], SUM6(qb, r));
        }
      }
      __syncthreads();
      if (g < 2) {
        for (int idx = tid; idx < 1024; idx += 256) {
          const int bl = idx >> 5, j = idx & 31;
          float v = (lds[0][idx] + lds[1][idx]) + (lds[2][idx] + lds[3][idx]);
          store_c4(&gb[(size_t)(mm * 32 + bl) * GBSTR + g * 1024 + js * 32 + j], v);
        }
      } else {
        for (int idx = tid; idx < 1024; idx += 256) {
          const int bl = idx >> 5, j = idx & 31;
          float vi = (lds[0][idx] + lds[1][idx]) + (lds[2][idx] + lds[3][idx]);
          float vh = (lds[4][idx] + lds[5][idx]) + (lds[6][idx] + lds[7][idx]);
          store_c4(&gb[(size_t)(mm * 32 + bl) * GBSTR + 2 * 1024 + js * 32 + j], vi);
          store_c4(&gb[(size_t)(mm * 32 + bl) * GBSTR + 3 * 1024 + js * 32 + j], vh);
        }
      }
    } else if (t > 0) {
      // attn tile: enc_w row t-1 from h slot (t&1)
      if (wid < 3) {
        DECL6(qa);
        for (int kc = wid; kc < H_ / 16; kc += 3) {
          LOADA_C(a0v, a1v, a2v, hp, HN, kc);
          CHUNK6(qa, a0v, a1v, a2v, atw_p, ATWN, kc);
        }
        WRITE_TILE(lds[wid], SUM6(qa, r));
      }
      __syncthreads();
      for (int idx = tid; idx < 1024; idx += 256) {
        const int bl = idx >> 5, j = idx & 31;
        float v = lds[0][idx] + lds[1][idx] + lds[2][idx] + attn_b[js * 32 + j];
        enc_w[((size_t)(mm * 32 + bl) * SRCL + (t - 1)) * H_ + js * 32 + j] = v;
      }
    }
    group_barrier(flags, fbase, grp, ++epoch, tid);

    // ---- phase B: h elementwise (GRU g==0 WGs => (mm, js)) ----
    if (isGRU && grp < 32) {
      short* h0w = h_pl + ((t + 1) & 1) * BH;
      for (int idx = tid; idx < 1024; idx += 256) {
        const int bl = idx >> 5, j = idx & 31;
        const int jg = js * 32 + j;
        const int bg = mm * 32 + bl;
        float rv  = load_c4f(&gb[(size_t)bg * GBSTR + jg]);
        float zv  = load_c4f(&gb[(size_t)bg * GBSTR + 1024 + jg]);
        float niv = load_c4f(&gb[(size_t)bg * GBSTR + 2048 + jg]);
        float nhv = load_c4f(&gb[(size_t)bg * GBSTR + 3072 + jg]);
        float pr   = rv + bih[jg] + bhh[jg];
        float pz   = zv + bih[H_ + jg] + bhh[H_ + jg];
        float gi_n = niv + bih[2 * H_ + jg];
        float gh_n = nhv + bhh[2 * H_ + jg];
        float r_ = sigm(pr), z_ = sigm(pz);
        float n_ = tanhf(gi_n + r_ * gh_n);
        float ho = h_f32[bg * H_ + jg];
        float hn = (1.f - z_) * n_ + z_ * ho;
        h_f32[bg * H_ + jg] = hn;            // enc-private
        publish_h(h0w, bg * H_ + jg, hn);
      }
    }
    group_barrier(flags, fbase, grp, ++epoch, tid);
  }

  // ---- final attn: enc_w row 499 from h slot 0 ----
  if (!isGRU) {
    const short* hp = h_pl + 0 * BH + hrow;
    if (wid < 3) {
      DECL6(qa);
      for (int kc = wid; kc < H_ / 16; kc += 3) {
        LOADA_C(a0v, a1v, a2v, hp, HN, kc);
        CHUNK6(qa, a0v, a1v, a2v, atw_p, ATWN, kc);
      }
      WRITE_TILE(lds[wid], SUM6(qa, r));
    }
    __syncthreads();
    for (int idx = tid; idx < 1024; idx += 256) {
      const int bl = idx >> 5, j = idx & 31;
      float v = lds[0][idx] + lds[1][idx] + lds[2][idx] + attn_b[js * 32 + j];
      enc_w[((size_t)(mm * 32 + bl) * SRCL + (SRCL - 1)) * H_ + js * 32 + j] = v;
    }
  }
}

// ---------------------------------------------------------------------------
// Decoder: 256 WGs x 256 thr, 4 phases/step.
//  P1: GRU tiles -> gate_buf.  P1b: h elementwise (grp<32).
//  P2: aux -> owW tile + tanh + fp64 sig partials; GRU g==1,js<16 -> outW.
//  P3: aux (batch b3): pt/alpha/context -> c planes.
// ---------------------------------------------------------------------------
__global__ __launch_bounds__(256) void dec_kernel(
    const float* __restrict__ trg, const short* __restrict__ Wih,
    const short* __restrict__ Whh, const float* __restrict__ bih,
    const float* __restrict__ bhh, const short* __restrict__ outW,
    const float* __restrict__ outb, const short* __restrict__ owW,
    const float* __restrict__ owb, const float* __restrict__ ovW,
    const float* __restrict__ ovb, const float* __restrict__ enc_w,
    float* __restrict__ h_f32, short* __restrict__ h_pl,
    short* __restrict__ c_pl, double* __restrict__ sig_part,
    float* __restrict__ gb, int* __restrict__ flags,
    float* __restrict__ out) {
  const int tid  = threadIdx.x;
  const int lane = tid & 63;
  const int wid  = tid >> 6;   // 0..3
  const int ra   = lane & 31;
  const int koff = (lane >> 5) * 8;
  const int bid  = blockIdx.x;

  const bool isGRU = bid < 192;
  int mm, g, js, grp;
  if (isGRU) {
    mm = bid / 96; grp = bid % 96; g = grp >> 5; js = grp & 31;
  } else {
    int aux = bid - 192; mm = aux >> 5; js = aux & 31; g = 0; grp = 96 + js;
  }
  const int fbase = mm * 128;

  __shared__ float lds[8][1024];
  __shared__ float al13[WIN];
  __shared__ float ah13[WIN];

  const int hrow = (mm * 32 + ra) * H_ + koff;
  const int nrow = g * H_ + js * 32 + ra;
  const short* wx_p = Wih + (size_t)nrow * (DIM + H_) + koff;
  const short* wc_p = wx_p + DIM;
  const short* wh_p = Whh + (size_t)nrow * H_ + koff;
  const float* trg_p = trg + (size_t)(mm * 32 + ra) * (TRGL * DIM) + koff;
  const short* cp = c_pl + hrow;
  const short* ow_p = owW + (size_t)(js * 32 + ra) * H_ + koff;
  const short* outw_p = outW + (size_t)((js & 15) * 32 + ra) * H_ + koff;
  const int b3 = mm * 32 + js;  // aux: batch

  int epoch = 0;
  for (int t = 0; t < TRGL; ++t) {
    const int rd = t & 1, wr = (t + 1) & 1;
    const short* hp = h_pl + rd * BH + hrow;

    // ---- P1: GRU tiles ----
    if (isGRU) {
      if (g < 2) {
        DECL6(qa);
        if (t > 0) {
          const float* xp = trg_p + (size_t)(t - 1) * DIM;
#pragma unroll 4
          for (int kc = wid * 8; kc < wid * 8 + 8; ++kc) {
            short8 a0v, a1v, a2v;
            split8(xp + kc * 16, a0v, a1v, a2v);
            CHUNK6(qa, a0v, a1v, a2v, wx_p, DWIHN, kc);
          }
        }
#pragma unroll 4
        for (int kc = wid * 16; kc < wid * 16 + 16; ++kc) {
          LOADA_C(a0v, a1v, a2v, cp, CN, kc);
          CHUNK6(qa, a0v, a1v, a2v, wc_p, DWIHN, kc);
        }
#pragma unroll 4
        for (int kc = wid * 16; kc < wid * 16 + 16; ++kc) {
          LOADA_C(a0v, a1v, a2v, hp, HN, kc);
          CHUNK6(qa, a0v, a1v, a2v, wh_p, DWHHN, kc);
        }
        WRITE_TILE(lds[wid], SUM6(qa, r));
      } else {
        {
          DECL6(qa);
          if (t > 0) {
            const float* xp = trg_p + (size_t)(t - 1) * DIM;
#pragma unroll 4
            for (int kc = wid * 8; kc < wid * 8 + 8; ++kc) {
              short8 a0v, a1v, a2v;
              split8(xp + kc * 16, a0v, a1v, a2v);
              CHUNK6(qa, a0v, a1v, a2v, wx_p, DWIHN, kc);
            }
          }
#pragma unroll 4
          for (int kc = wid * 16; kc < wid * 16 + 16; ++kc) {
            LOADA_C(a0v, a1v, a2v, cp, CN, kc);
            CHUNK6(qa, a0v, a1v, a2v, wc_p, DWIHN, kc);
          }
          WRITE_TILE(lds[wid], SUM6(qa, r));
        }
        {
          DECL6(qb);
#pragma unroll 4
          for (int kc = wid * 16; kc < wid * 16 + 16; ++kc) {
            LOADA_C(a0v, a1v, a2v, hp, HN, kc);
            CHUNK6(qb, a0v, a1v, a2v, wh_p, DWHHN, kc);
          }
          WRITE_TILE(lds[4 + wid], SUM6(qb, r));
        }
      }
      __syncthreads();
      if (g < 2) {
        for (int idx = tid; idx < 1024; idx += 256) {
          const int bl = idx >> 5, j = idx & 31;
          float v = (lds[0][idx] + lds[1][idx]) + (lds[2][idx] + lds[3][idx]);
          store_c4(&gb[(size_t)(mm * 32 + bl) * GBSTR + g * 1024 + js * 32 + j], v);
        }
      } else {
        for (int idx = tid; idx < 1024; idx += 256) {
          const int bl = idx >> 5, j = idx & 31;
          float vi = (lds[0][idx] + lds[1][idx]) + (lds[2][idx] + lds[3][idx]);
          float vh = (lds[4][idx] + lds[5][idx]) + (lds[6][idx] + lds[7][idx]);
          store_c4(&gb[(size_t)(mm * 32 + bl) * GBSTR + 2 * 1024 + js * 32 + j], vi);
          store_c4(&gb[(size_t)(mm * 32 + bl) * GBSTR + 3 * 1024 + js * 32 + j], vh);
        }
      }
    }
    group_barrier(flags, fbase, grp, ++epoch, tid);

    // ---- P1b: h elementwise (grp<32 => (mm, js)) ----
    if (isGRU && grp < 32) {
      short* h0w = h_pl + wr * BH;
      for (int idx = tid; idx < 1024; idx += 256) {
        const int bl = idx >> 5, j = idx & 31;
        const int jg = js * 32 + j;
        const int bg = mm * 32 + bl;
        float rv  = load_c4f(&gb[(size_t)bg * GBSTR + jg]);
        float zv  = load_c4f(&gb[(size_t)bg * GBSTR + 1024 + jg]);
        float niv = load_c4f(&gb[(size_t)bg * GBSTR + 2048 + jg]);
        float nhv = load_c4f(&gb[(size_t)bg * GBSTR + 3072 + jg]);
        float pr   = rv + bih[jg] + bhh[jg];
        float pz   = zv + bih[H_ + jg] + bhh[H_ + jg];
        float gi_n = niv + bih[2 * H_ + jg];
        float gh_n = nhv + bhh[2 * H_ + jg];
        float r_ = sigm(pr), z_ = sigm(pz);
        float n_ = tanhf(gi_n + r_ * gh_n);
        float ho = load_c4f(&h_f32[bg * H_ + jg]);
        float hn = (1.f - z_) * n_ + z_ * ho;
        store_c4(&h_f32[bg * H_ + jg], hn);
        publish_h(h0w, bg * H_ + jg, hn);
      }
    }
    group_barrier(flags, fbase, grp, ++epoch, tid);

    // ---- P2 ----
    const short* hc = h_pl + wr * BH + hrow;
    if (!isGRU) {
      // ow tile (mm, js): GEMM -> tanh -> fp64 sig partials
      if (wid < 3) {
        DECL6(qt);
        for (int kc = wid; kc < H_ / 16; kc += 3) {
          LOADA_C(a0v, a1v, a2v, hc, HN, kc);
          CHUNK6(qt, a0v, a1v, a2v, ow_p, OWWN, kc);
        }
        WRITE_TILE(lds[wid], SUM6(qt, r));
      }
      __syncthreads();
      for (int idx = tid; idx < 1024; idx += 256) {
        float s3 = lds[0][idx] + lds[1][idx] + lds[2][idx] +
                   owb[js * 32 + (idx & 31)];
        lds[0][idx] = tanhf(s3);
      }
      __syncthreads();
      if (tid < 32) {
        double sv = 0.0;
#pragma unroll 8
        for (int j = 0; j < 32; ++j)
          sv += (double)lds[0][tid * 32 + j] * (double)ovW[js * 32 + j];
        store_c8(&sig_part[(size_t)(t * 32 + js) * B_ + mm * 32 + tid], sv);
      }
    } else if (g == 1 && js < 16) {
      // outW tile (mm, jo=js)
      if (wid < 3) {
        DECL6(qy);
        for (int kc = wid; kc < H_ / 16; kc += 3) {
          LOADA_C(a0v, a1v, a2v, hc, HN, kc);
          CHUNK6(qy, a0v, a1v, a2v, outw_p, OUTWN, kc);
        }
        WRITE_TILE(lds[wid], SUM6(qy, r));
      }
      __syncthreads();
      for (int idx = tid; idx < 1024; idx += 256) {
        const int bl = idx >> 5, j = idx & 31;
        const int d = js * 32 + j;
        float v = lds[0][idx] + lds[1][idx] + lds[2][idx] + outb[d];
        out[(size_t)(mm * 32 + bl) * (TRGL * DIM) + (size_t)t * DIM + d] = v;
      }
    }
    group_barrier(flags, fbase, grp, ++epoch, tid);

    // ---- P3: aux WG = batch b3 ----
    if (!isGRU) {
      double sigv = (double)ovb[0];
      for (int p = 0; p < 32; ++p)  // fixed order: deterministic
        sigv += load_c8d(&sig_part[(size_t)(t * 32 + p) * B_ + b3]);
      const double ptv = 487.0 / (1.0 + exp(-sigv)) + 6.0;
      const int center = (int)ptv;  // floor (pt > 0)
      const int row0 = center - DW;
      const float ptf = (float)ptv;
      const float* s_vec = h_f32 + b3 * H_;
      if (wid < 3) {
        for (int w = wid; w < WIN; w += 3) {
          const float* ew =
              enc_w + ((size_t)b3 * SRCL + row0 + w) * H_ + lane * 16;
          float part = 0.f;
#pragma unroll
          for (int i = 0; i < 16; ++i)
            part += ew[i] * load_c4f(&s_vec[lane * 16 + i]);
#pragma unroll
          for (int off = 32; off; off >>= 1) part += __shfl_xor(part, off, 64);
          if (lane == 0) ah13[w] = part;
        }
      }
      __syncthreads();
      if (tid == 0) {
        float v[WIN], mx = -1e30f;
#pragma unroll
        for (int w = 0; w < WIN; ++w) {
          const float dd = (float)(row0 + w) - ptf;
          v[w] = ah13[w] * expf(-(dd * dd) / 18.f);
          mx = fmaxf(mx, v[w]);
        }
        float ssum = 0.f;
#pragma unroll
        for (int w = 0; w < WIN; ++w) { v[w] = expf(v[w] - mx); ssum += v[w]; }
        const float inv = 1.f / ssum;
#pragma unroll
        for (int w = 0; w < WIN; ++w) al13[w] = v[w] * inv;
      }
      __syncthreads();
      for (int hh = tid; hh < H_; hh += 256) {
        const float* ewb = enc_w + ((size_t)b3 * SRCL + row0) * H_ + hh;
        float acc = 0.f;
#pragma unroll
        for (int w = 0; w < WIN; ++w) acc += al13[w] * ewb[(size_t)w * H_];
        short s0 = f2bf(acc);
        float rr = acc - bf2f(s0);
        short s1 = f2bf(rr);
        store_c2(&c_pl[b3 * H_ + hh], s0);
        store_c2(&c_pl[CN + b3 * H_ + hh], s1);
        store_c2(&c_pl[2 * CN + b3 * H_ + hh], f2bf(rr - bf2f(s1)));
      }
    }
    group_barrier(flags, fbase, grp, ++epoch, tid);
  }
}

extern "C" void kernel_launch(void* const* d_in, const int* in_sizes, int n_in,
                              void* d_out, int out_size, void* d_ws,
                              size_t ws_size, hipStream_t stream) {
  (void)in_sizes; (void)n_in; (void)out_size; (void)ws_size;

  const float* src     = (const float*)d_in[0];
  const float* trg     = (const float*)d_in[1];
  const float* enc_Wih = (const float*)d_in[2];
  const float* enc_Whh = (const float*)d_in[3];
  const float* enc_bih = (const float*)d_in[4];
  const float* enc_bhh = (const float*)d_in[5];
  const float* dec_Wih = (const float*)d_in[6];
  const float* dec_Whh = (const float*)d_in[7];
  const float* dec_bih = (const float*)d_in[8];
  const float* dec_bhh = (const float*)d_in[9];
  const float* out_W   = (const float*)d_in[10];
  const float* out_b   = (const float*)d_in[11];
  const float* ow_W    = (const float*)d_in[12];
  const float* ow_b    = (const float*)d_in[13];
  const float* ov_W    = (const float*)d_in[14];
  const float* ov_b    = (const float*)d_in[15];
  const float* attn_W  = (const float*)d_in[16];
  const float* attn_b  = (const float*)d_in[17];

  char* ws = (char*)d_ws;
  size_t off = 0;
  auto take = [&](size_t bytes) {
    size_t o = off;
    off += (bytes + 255) & ~(size_t)255;
    return o;
  };

  // --- zeroed state region ---
  float* h_f32   = (float*)(ws + take(BH * 4));
  short* h_pl    = (short*)(ws + take((size_t)3 * HN * 2));
  short* c_pl    = (short*)(ws + take((size_t)3 * CN * 2));
  int*   flags_e = (int*)(ws + take(256 * 4));
  int*   flags_d = (int*)(ws + take(256 * 4));
  const size_t zero_bytes = off;

  // --- non-zeroed ---
  double* sig_part = (double*)(ws + take((size_t)TRGL * 32 * B_ * 8));
  float* gate_buf  = (float*)(ws + take((size_t)B_ * GBSTR * 4));
  short* pWihE = (short*)(ws + take((size_t)3 * EWIHN * 2));
  short* pWhhE = (short*)(ws + take((size_t)3 * EWHHN * 2));
  short* pWihD = (short*)(ws + take((size_t)3 * DWIHN * 2));
  short* pWhhD = (short*)(ws + take((size_t)3 * DWHHN * 2));
  short* pOutW = (short*)(ws + take((size_t)3 * OUTWN * 2));
  short* pOwW  = (short*)(ws + take((size_t)3 * OWWN * 2));
  short* pAtW  = (short*)(ws + take((size_t)3 * ATWN * 2));
  float* enc_w = (float*)(ws + take((size_t)B_ * SRCL * H_ * 4));

  hipMemsetAsync(ws, 0, zero_bytes, stream);

  auto split = [&](const float* in, short* outp, int n) {
    split3_kernel<<<dim3((n + 255) / 256), dim3(256), 0, stream>>>(in, outp, n);
  };
  split(enc_Wih, pWihE, EWIHN);
  split(enc_Whh, pWhhE, EWHHN);
  split(dec_Wih, pWihD, DWIHN);
  split(dec_Whh, pWhhD, DWHHN);
  split(out_W,  pOutW, OUTWN);
  split(ow_W,   pOwW,  OWWN);
  split(attn_W, pAtW,  ATWN);

  enc_kernel<<<dim3(256), dim3(256), 0, stream>>>(
      src, pWihE, pWhhE, enc_bih, enc_bhh, pAtW, attn_b, h_f32, h_pl, enc_w,
      gate_buf, flags_e);

  dec_kernel<<<dim3(256), dim3(256), 0, stream>>>(
      trg, pWihD, pWhhD, dec_bih, dec_bhh, pOutW, out_b, pOwW, ow_b, ov_W,
      ov_b, enc_w, h_f32, h_pl, c_pl, sig_part, gate_buf, flags_d,
      (float*)d_out);
}